// Round 12
// baseline (837.638 us; speedup 1.0000x reference)
//
#include <hip/hip_runtime.h>
#include <cstdint>
#include <cstddef>

#define N_NODES 20000
#define N_EDGES 160000
#define IN_CH   128
#define NH      16
#define CD      32
#define HC      512   // NH*CD
#define ED      93
#define EDP     96    // ED padded to multiple of 32
#define NB      64
#define NCAT    2048  // q|k|v|skip GEMM output cols (all bf16)

typedef __attribute__((ext_vector_type(8))) short short8;
typedef __attribute__((ext_vector_type(4))) float f32x4;
typedef unsigned short ushort_t;

// ---------------------------------------------------------------- utilities

__device__ inline void atomicMaxF(float* addr, float val) {
    unsigned int* ua = (unsigned int*)addr;
    unsigned int old = *ua;
    while (__uint_as_float(old) < val) {
        unsigned int assumed = old;
        old = atomicCAS(ua, assumed, __float_as_uint(val));
        if (old == assumed) break;
    }
}

__device__ inline ushort_t f2bf(float f) {
    unsigned int u = __float_as_uint(f);
    u = (u + 0x7FFF + ((u >> 16) & 1)) >> 16;   // RNE
    return (ushort_t)u;
}
__device__ inline float bf2f(ushort_t u) {
    return __uint_as_float((unsigned)u << 16);
}
__device__ inline void unpack8(uint4 u, float* o) {
    o[0] = bf2f((ushort_t)(u.x & 0xffff)); o[1] = bf2f((ushort_t)(u.x >> 16));
    o[2] = bf2f((ushort_t)(u.y & 0xffff)); o[3] = bf2f((ushort_t)(u.y >> 16));
    o[4] = bf2f((ushort_t)(u.z & 0xffff)); o[5] = bf2f((ushort_t)(u.z >> 16));
    o[6] = bf2f((ushort_t)(u.w & 0xffff)); o[7] = bf2f((ushort_t)(u.w >> 16));
}

// async global->LDS, 16B per lane; lds dest = wave-uniform base + lane*16
__device__ inline void gload_lds16(const void* g, void* l) {
    __builtin_amdgcn_global_load_lds(
        (const __attribute__((address_space(1))) void*)g,
        (__attribute__((address_space(3))) void*)l, 16, 0, 0);
}

__global__ void k_fill(float* __restrict__ p, float v, int n) {
    int i = blockIdx.x * blockDim.x + threadIdx.x;
    int stride = gridDim.x * blockDim.x;
    for (; i < n; i += stride) p[i] = v;
}
__global__ void k_zero_i(int* __restrict__ p, int n) {
    int i = blockIdx.x * blockDim.x + threadIdx.x;
    int stride = gridDim.x * blockDim.x;
    for (; i < n; i += stride) p[i] = 0;
}
__global__ void k_copy_i(const int* __restrict__ a, int* __restrict__ b, int n) {
    int i = blockIdx.x * blockDim.x + threadIdx.x;
    int stride = gridDim.x * blockDim.x;
    for (; i < n; i += stride) b[i] = a[i];
}

// f32 [M,K] -> bf16 [M,Kp] zero-padded rows
__global__ void k_cvt_pad(const float* __restrict__ in, ushort_t* __restrict__ out,
                          int M, int K, int Kp) {
    int i = blockIdx.x * blockDim.x + threadIdx.x;
    int stride = gridDim.x * blockDim.x;
    int total = M * Kp;
    for (; i < total; i += stride) {
        int m = i / Kp, k = i - m * Kp;
        out[i] = (k < K) ? f2bf(in[(size_t)m * K + k]) : (ushort_t)0;
    }
}

// W [K,N] f32 -> Wt [N,Kp] bf16 (transpose + pad)
__global__ void k_cvt_wt(const float* __restrict__ W, ushort_t* __restrict__ Wt,
                         int K, int N, int Kp) {
    int i = blockIdx.x * blockDim.x + threadIdx.x;
    int stride = gridDim.x * blockDim.x;
    int total = N * Kp;
    for (; i < total; i += stride) {
        int n = i / Kp, k = i - n * Kp;
        Wt[i] = (k < K) ? f2bf(W[(size_t)k * N + n]) : (ushort_t)0;
    }
}

// bcat[2048] = bq|bk|bv|bs
__global__ void k_bcat(const float* __restrict__ bq, const float* __restrict__ bk,
                       const float* __restrict__ bv, const float* __restrict__ bs,
                       float* __restrict__ out) {
    int i = blockIdx.x * blockDim.x + threadIdx.x;
    if (i >= NCAT) return;
    int s = i >> 9, j = i & 511;
    float v = (s == 0) ? bq[j] : (s == 1) ? bk[j] : (s == 2) ? bv[j] : bs[j];
    out[i] = v;
}

// ---------------------------------------------------------------- CSR build

__global__ void k_hist(const int* __restrict__ dst, int* __restrict__ deg) {
    int i = blockIdx.x * blockDim.x + threadIdx.x;
    if (i < N_EDGES) atomicAdd(&deg[dst[i]], 1);
}

__global__ __launch_bounds__(1024) void k_scan(const int* __restrict__ deg,
                                               int* __restrict__ rowptr) {
    __shared__ int part[1024];
    int t = threadIdx.x;
    int base = t * 20;
    int loc[20];
    int s = 0;
#pragma unroll
    for (int i = 0; i < 20; ++i) {
        int idx = base + i;
        int v = (idx < N_NODES) ? deg[idx] : 0;
        loc[i] = s; s += v;
    }
    part[t] = s;
    __syncthreads();
    for (int off = 1; off < 1024; off <<= 1) {
        int v = (t >= off) ? part[t - off] : 0;
        __syncthreads();
        part[t] += v;
        __syncthreads();
    }
    int pre = (t > 0) ? part[t - 1] : 0;
#pragma unroll
    for (int i = 0; i < 20; ++i) {
        int idx = base + i;
        if (idx < N_NODES) rowptr[idx] = pre + loc[i];
    }
    if (t == 1023) rowptr[N_NODES] = part[1023];
}

__global__ void k_scatter(const int* __restrict__ src, const int* __restrict__ dst,
                          int* __restrict__ cursor, int* __restrict__ perm,
                          int* __restrict__ psrc) {
    int i = blockIdx.x * blockDim.x + threadIdx.x;
    if (i >= N_EDGES) return;
    int d = dst[i];
    int p = atomicAdd(&cursor[d], 1);
    perm[p] = i;
    psrc[p] = src[i];
}

// ---------------------------------------------------------------- MFMA GEMM (QKVS)
// Yb[M,N](bf16) = A[M,K](bf16) @ Bt[N,K]^T + bias. BK=64, 128x128 tile, 4 waves.
// 1-D grid n-fastest + bijective XCD swizzle. LDS rows 128B.
// Staging via global_load_lds: linear LDS dest, PRE-SWIZZLED global source
// (lane fetches unit u^r so that LDS[row][phys u] = global[row][u^(row&7)]),
// matching the MFMA-read swizzle ^(row&7).
// Epilogue: LDS bounce (XOR-swizzled) -> 128B/thread coalesced stores.

__global__ __launch_bounds__(256) void k_mfma_gemm(
    const ushort_t* __restrict__ A, const ushort_t* __restrict__ Bt,
    const float* __restrict__ bias, ushort_t* __restrict__ Yb,
    int M, int K, int N) {
    __shared__ char smem[32768];
    char* As = smem;
    char* Bs = smem + 16384;

    int tid  = threadIdx.x;
    int lane = tid & 63, wave = tid >> 6;
    int l15 = lane & 15, lg = lane >> 4;
    int nt = N >> 7;
    int nwg = gridDim.x;
    int bid = blockIdx.x;
    int wg;
    if ((nwg & 7) == 0) { int cpx = nwg >> 3; wg = (bid & 7) * cpx + (bid >> 3); }
    else wg = bid;
    int bm = (wg / nt) * 128, bn = (wg % nt) * 128;
    int wm = (wave >> 1) * 64, wn = (wave & 1) * 64;

    f32x4 acc[4][4] = {};

    // staging lane decomposition: r = sub-row (0..7), up = 16B slot, gu = source unit
    int sr = lane >> 3;
    int su = lane & 7;
    int gu = su ^ sr;

    for (int k0 = 0; k0 < K; k0 += 64) {
#pragma unroll
        for (int i = 0; i < 4; ++i) {
            int rloc = wave * 32 + i * 8;          // wave-uniform row base
            int row = rloc + sr;                   // per-lane row
            // A (guard M edge per-lane; stale LDS only feeds discarded rows)
            if (bm + row < M)
                gload_lds16(A + (size_t)(bm + row) * K + k0 + gu * 8, As + rloc * 128);
            // B (always in-bounds: N multiple of 128)
            gload_lds16(Bt + (size_t)(bn + row) * K + k0 + gu * 8, Bs + rloc * 128);
        }
        __syncthreads();

#pragma unroll
        for (int ks = 0; ks < 2; ++ks) {
            short8 af[4], bfr[4];
#pragma unroll
            for (int mr = 0; mr < 4; ++mr) {
                int r = wm + mr * 16 + l15;
                af[mr] = *(const short8*)(As + r * 128 + (((ks * 4 + lg) ^ (r & 7)) << 4));
            }
#pragma unroll
            for (int nc = 0; nc < 4; ++nc) {
                int r = wn + nc * 16 + l15;
                bfr[nc] = *(const short8*)(Bs + r * 128 + (((ks * 4 + lg) ^ (r & 7)) << 4));
            }
#pragma unroll
            for (int mr = 0; mr < 4; ++mr)
#pragma unroll
                for (int nc = 0; nc < 4; ++nc)
                    acc[mr][nc] = __builtin_amdgcn_mfma_f32_16x16x32_bf16(
                        af[mr], bfr[nc], acc[mr][nc], 0, 0, 0);
        }
        __syncthreads();
    }

    // epilogue: bf16 C tile into LDS (128 rows x 256B, 16B-unit XOR swizzle)
    char* Cs = smem;
#pragma unroll
    for (int mr = 0; mr < 4; ++mr) {
#pragma unroll
        for (int nc = 0; nc < 4; ++nc) {
            int coll = wn + nc * 16 + l15;
            float b = bias ? bias[bn + coll] : 0.f;
            int u0 = coll >> 3;
#pragma unroll
            for (int j = 0; j < 4; ++j) {
                int row = wm + mr * 16 + lg * 4 + j;
                int u = u0 ^ (row & 7);
                *(ushort_t*)(Cs + row * 256 + (u << 4) + ((coll & 7) << 1)) =
                    f2bf(acc[mr][nc][j] + b);
            }
        }
    }
    __syncthreads();
    {
        int row = tid >> 1;
        int hf = tid & 1;
        int gr = bm + row;
        if (gr < M) {
            uint4* d = (uint4*)(Yb + (size_t)gr * N + bn + hf * 64);
#pragma unroll
            for (int i = 0; i < 8; ++i) {
                int u = (hf * 8 + i) ^ (row & 7);
                d[i] = *(const uint4*)(Cs + row * 256 + (u << 4));
            }
        }
    }
}

// ---------------------------------------------------------------- edge GEMM
// eb[r, :512] = ea_b[perm[e0+r], :96] @ We[512,96]^T (bf16). Full-K single-stage.

#define EG_LDSB 49152

__global__ __launch_bounds__(256) void k_egemm(
    const ushort_t* __restrict__ Ab, const ushort_t* __restrict__ Bt,
    ushort_t* __restrict__ Yb, const int* __restrict__ perm,
    int pbase, int ec) {
    __shared__ char smem[EG_LDSB];
    char* As = smem;
    char* Bs = smem + 24576;

    int tid  = threadIdx.x;
    int lane = tid & 63, wave = tid >> 6;
    int l15 = lane & 15, lg = lane >> 4;
    int nwg = gridDim.x;
    int bid = blockIdx.x;
    int wg;
    if ((nwg & 7) == 0) { int cpx = nwg >> 3; wg = (bid & 7) * cpx + (bid >> 3); }
    else wg = bid;
    int bm = (wg >> 2) * 128;
    int n0 = (wg & 3) * 128;
    int wm = (wave >> 1) * 64, wn = (wave & 1) * 64;

    int srow = tid >> 1;
    int h    = tid & 1;
    int ssw  = ((srow >> 1) & 3) << 4;
    {
        int gm = bm + srow;
        uint4 va[6];
#pragma unroll
        for (int i = 0; i < 6; ++i) { va[i].x = va[i].y = va[i].z = va[i].w = 0; }
        if (gm < ec) {
            int ar = perm[pbase + gm];
            const uint4* ga = (const uint4*)(Ab + (size_t)ar * EDP + h * 48);
#pragma unroll
            for (int i = 0; i < 6; ++i) va[i] = ga[i];
        }
        char* dsta = As + srow * 192;
#pragma unroll
        for (int i = 0; i < 6; ++i) {
            int c = h * 96 + i * 16;
            *(uint4*)(dsta + ((c & ~63) | ((c & 63) ^ ssw))) = va[i];
        }
        uint4 vb[6];
        {
            const uint4* gb = (const uint4*)(Bt + (size_t)(n0 + srow) * EDP + h * 48);
#pragma unroll
            for (int i = 0; i < 6; ++i) vb[i] = gb[i];
        }
        char* dstb = Bs + srow * 192;
#pragma unroll
        for (int i = 0; i < 6; ++i) {
            int c = h * 96 + i * 16;
            *(uint4*)(dstb + ((c & ~63) | ((c & 63) ^ ssw))) = vb[i];
        }
    }
    __syncthreads();

    int fsw = ((l15 >> 1) & 3) << 4;

    f32x4 acc[4][4] = {};
#pragma unroll
    for (int ks = 0; ks < 3; ++ks) {
        short8 af[4], bfr[4];
#pragma unroll
        for (int mr = 0; mr < 4; ++mr) {
            int r = wm + mr * 16 + l15;
            int c = ks * 64 + ((lg * 16) ^ fsw);
            af[mr] = *(const short8*)(As + r * 192 + c);
        }
#pragma unroll
        for (int nc = 0; nc < 4; ++nc) {
            int r = wn + nc * 16 + l15;
            int c = ks * 64 + ((lg * 16) ^ fsw);
            bfr[nc] = *(const short8*)(Bs + r * 192 + c);
        }
#pragma unroll
        for (int mr = 0; mr < 4; ++mr)
#pragma unroll
            for (int nc = 0; nc < 4; ++nc)
                acc[mr][nc] = __builtin_amdgcn_mfma_f32_16x16x32_bf16(
                    af[mr], bfr[nc], acc[mr][nc], 0, 0, 0);
    }
    __syncthreads();

    char* Cs = smem;   // 128 * 288 = 36864
#pragma unroll
    for (int mr = 0; mr < 4; ++mr) {
#pragma unroll
        for (int nc = 0; nc < 4; ++nc) {
            int col = wn + nc * 16 + l15;
#pragma unroll
            for (int j = 0; j < 4; ++j) {
                int row = wm + mr * 16 + lg * 4 + j;
                *(ushort_t*)(Cs + row * 288 + col * 2) = f2bf(acc[mr][nc][j]);
            }
        }
    }
    __syncthreads();

    {
        int row = tid >> 1;
        int halfc = tid & 1;
        if (bm + row < ec) {
            const uint4* srcp = (const uint4*)(Cs + row * 288 + halfc * 128);
            uint4* dstg = (uint4*)(Yb + (size_t)(bm + row) * HC + n0 + halfc * 64);
#pragma unroll
            for (int i = 0; i < 8; ++i) dstg[i] = srcp[i];
        }
    }
}

// ---------------------------------------------------------------- fused edge phase
// One block (128 thr = 2 waves) per dst node. Wave w handles edges lo+w, lo+w+2,...
// Each lane owns 8 channels (16B loads). Online softmax; LDS merge of 2 states.
// fresh = node's first chunk -> init state in-register (no macc/mbuf read).

__global__ __launch_bounds__(128) void k_edge(
    const ushort_t* __restrict__ qkvs, const ushort_t* __restrict__ eb,
    const int* __restrict__ psrc, const int* __restrict__ rowptr,
    float* __restrict__ macc, float* __restrict__ mbuf, float* __restrict__ dbuf,
    int e0, int e1) {
    int n = blockIdx.x;
    int beg = rowptr[n], end = rowptr[n + 1];
    int lo = beg > e0 ? beg : e0;
    int hi = end < e1 ? end : e1;
    if (lo >= hi) return;

    int t = threadIdx.x;
    int w = t >> 6;
    int lane = t & 63;
    int c0 = lane * 8;
    int h = lane >> 2;
    bool fresh = (beg >= e0);

    float q[8];
    unpack8(*(const uint4*)(qkvs + (size_t)n * NCAT + c0), q);

    float mm, dd, a[8];
    if (w == 0 && !fresh) {
        mm = mbuf[n * NH + h];
        dd = dbuf[n * NH + h];
        float4 a0 = *(const float4*)(macc + (size_t)n * HC + c0);
        float4 a1 = *(const float4*)(macc + (size_t)n * HC + c0 + 4);
        a[0] = a0.x; a[1] = a0.y; a[2] = a0.z; a[3] = a0.w;
        a[4] = a1.x; a[5] = a1.y; a[6] = a1.z; a[7] = a1.w;
    } else {
        mm = -1e30f; dd = 0.f;
#pragma unroll
        for (int j = 0; j < 8; ++j) a[j] = 0.f;
    }

    int i = lo + w;
    uint4 ku4, vu4, eu4;
    if (i < hi) {
        int sn = psrc[i];
        ku4 = *(const uint4*)(qkvs + (size_t)sn * NCAT + 512 + c0);
        vu4 = *(const uint4*)(qkvs + (size_t)sn * NCAT + 1024 + c0);
        eu4 = *(const uint4*)(eb + (size_t)(i - e0) * HC + c0);
    }
    while (i < hi) {
        uint4 kc = ku4, vc = vu4, ec = eu4;
        int inext = i + 2;
        if (inext < hi) {
            int sn2 = psrc[inext];
            ku4 = *(const uint4*)(qkvs + (size_t)sn2 * NCAT + 512 + c0);
            vu4 = *(const uint4*)(qkvs + (size_t)sn2 * NCAT + 1024 + c0);
            eu4 = *(const uint4*)(eb + (size_t)(inext - e0) * HC + c0);
        }
        float kk[8], vv[8], ee[8];
        unpack8(kc, kk); unpack8(vc, vv); unpack8(ec, ee);
        float part = 0.f;
#pragma unroll
        for (int j = 0; j < 8; ++j) part += q[j] * (kk[j] + ee[j]);
        part += __shfl_xor(part, 1);
        part += __shfl_xor(part, 2);
        float s = part * 0.17677669529663687f;   // /sqrt(32)
        float mn = fmaxf(mm, s);
        float sc = __expf(mm - mn);
        float p  = __expf(s - mn);
        dd = dd * sc + p;
        mm = mn;
#pragma unroll
        for (int j = 0; j < 8; ++j) a[j] = a[j] * sc + p * (vv[j] + ee[j]);
        i = inext;
    }

    // merge the two wave states
    __shared__ float sm_acc[512];
    __shared__ float sm_m[16];
    __shared__ float sm_d[16];
    if (w == 1) {
#pragma unroll
        for (int j = 0; j < 8; ++j) sm_acc[c0 + j] = a[j];
        if ((lane & 3) == 0) { sm_m[h] = mm; sm_d[h] = dd; }
    }
    __syncthreads();
    if (w == 0) {
        float m1 = sm_m[h], d1 = sm_d[h];
        float M = fmaxf(mm, m1);
        float sc0 = __expf(mm - M);
        float sc1 = __expf(m1 - M);
        dd = dd * sc0 + d1 * sc1;
        float4 o0, o1;
        o0.x = a[0] * sc0 + sm_acc[c0 + 0] * sc1;
        o0.y = a[1] * sc0 + sm_acc[c0 + 1] * sc1;
        o0.z = a[2] * sc0 + sm_acc[c0 + 2] * sc1;
        o0.w = a[3] * sc0 + sm_acc[c0 + 3] * sc1;
        o1.x = a[4] * sc0 + sm_acc[c0 + 4] * sc1;
        o1.y = a[5] * sc0 + sm_acc[c0 + 5] * sc1;
        o1.z = a[6] * sc0 + sm_acc[c0 + 6] * sc1;
        o1.w = a[7] * sc0 + sm_acc[c0 + 7] * sc1;
        *(float4*)(macc + (size_t)n * HC + c0) = o0;
        *(float4*)(macc + (size_t)n * HC + c0 + 4) = o1;
        if ((lane & 3) == 0) { mbuf[n * NH + h] = M; dbuf[n * NH + h] = dd; }
    }
}

// x_out = leaky_relu(macc/d + skip, 0.2); skip read bf16 from qkvs[:,1536:2048]
__global__ void k_epi2(const float* __restrict__ macc, const float* __restrict__ dbuf,
                       const ushort_t* __restrict__ qkvs, float* __restrict__ xout,
                       ushort_t* __restrict__ xoutb, int n) {
    int i = blockIdx.x * blockDim.x + threadIdx.x;
    int stride = gridDim.x * blockDim.x;
    for (; i < n; i += stride) {
        int node = i >> 9, c = i & (HC - 1);
        int h = c >> 5;
        float dd = dbuf[node * NH + h];
        float msg = (dd > 0.f) ? macc[i] / dd : 0.f;
        float sk = bf2f(qkvs[(size_t)node * NCAT + 1536 + c]);
        float v = msg + sk;
        v = v >= 0.f ? v : 0.2f * v;
        xout[i] = v;
        if (xoutb) xoutb[i] = f2bf(v);
    }
}

// ---------------------------------------------------------------- pooling

__global__ __launch_bounds__(256) void k_pool2(
    const float* __restrict__ x, const int* __restrict__ batch,
    float* __restrict__ psum, float* __restrict__ pmax, int* __restrict__ cnt) {
    int b = blockIdx.x;
    int s = blockIdx.y;
    int lo = 0, hi = N_NODES;
    while (lo < hi) { int mid = (lo + hi) >> 1; if (batch[mid] < b) lo = mid + 1; else hi = mid; }
    int beg = lo;
    hi = N_NODES;
    while (lo < hi) { int mid = (lo + hi) >> 1; if (batch[mid] < b + 1) lo = mid + 1; else hi = mid; }
    int end = lo;
    if (s == 0 && threadIdx.x == 0) cnt[b] = end - beg;
    int cn = end - beg;
    int per = (cn + 7) >> 3;
    int nb = beg + s * per;
    int ne = nb + per; if (ne > end) ne = end;
    if (nb >= ne) return;
    int c0 = threadIdx.x * 2;
    float s0 = 0.f, s1 = 0.f, m0 = -1e30f, m1 = -1e30f;
    for (int n = nb; n < ne; ++n) {
        float2 v = *(const float2*)(x + (size_t)n * HC + c0);
        s0 += v.x; s1 += v.y;
        m0 = fmaxf(m0, v.x); m1 = fmaxf(m1, v.y);
    }
    atomicAdd(&psum[b * HC + c0], s0);
    atomicAdd(&psum[b * HC + c0 + 1], s1);
    atomicMaxF(&pmax[b * HC + c0], m0);
    atomicMaxF(&pmax[b * HC + c0 + 1], m1);
}

__global__ void k_poolfin(const float* __restrict__ psum, const float* __restrict__ pmax,
                          const int* __restrict__ cnt, float* __restrict__ hsum, int mode) {
    int i = blockIdx.x * blockDim.x + threadIdx.x;
    if (i >= NB * 1024) return;
    int b = i >> 10, c = i & 1023;
    float val;
    if (c < HC) {
        int ct = cnt[b];
        val = psum[b * HC + c] / (float)(ct > 0 ? ct : 1);
    } else {
        val = pmax[b * HC + (c - HC)];
    }
    if (mode == 0) hsum[i] = val;
    else hsum[i] += val;
}

// ---------------------------------------------------------------- MLP head

__global__ __launch_bounds__(256) void k_head(
    const float* __restrict__ hsum, const float* __restrict__ fc1W,
    const float* __restrict__ fc1b, const float* __restrict__ fc2W,
    const float* __restrict__ fc2b, float* __restrict__ out) {
    int b = blockIdx.x;
    int j = threadIdx.x;
    __shared__ float hs[256];
    float acc = fc1b[j];
    const float* hin = hsum + (size_t)b * 1024;
    for (int k = 0; k < 1024; ++k) {
        acc += hin[k] * fc1W[(size_t)k * 256 + j];
    }
    hs[j] = fmaxf(acc, 0.f);
    __syncthreads();
    if (j < 32) {
        float o = fc2b[j];
        for (int k = 0; k < 256; ++k) o += hs[k] * fc2W[(size_t)k * 32 + j];
        out[b * 32 + j] = o;
    }
}

// ---------------------------------------------------------------- driver

extern "C" void kernel_launch(void* const* d_in, const int* in_sizes, int n_in,
                              void* d_out, int out_size, void* d_ws, size_t ws_size,
                              hipStream_t stream) {
    const float* x      = (const float*)d_in[0];
    const float* ea     = (const float*)d_in[1];
    const int*   ei     = (const int*)d_in[2];
    const int*   batch  = (const int*)d_in[3];
    const int* src = ei;
    const int* dst = ei + N_EDGES;

    const float* t1_Wq = (const float*)d_in[4];
    const float* t1_bq = (const float*)d_in[5];
    const float* t1_Wk = (const float*)d_in[6];
    const float* t1_bk = (const float*)d_in[7];
    const float* t1_Wv = (const float*)d_in[8];
    const float* t1_bv = (const float*)d_in[9];
    const float* t1_We = (const float*)d_in[10];
    const float* t1_Ws = (const float*)d_in[11];
    const float* t1_bs = (const float*)d_in[12];
    const float* t2_Wq = (const float*)d_in[13];
    const float* t2_bq = (const float*)d_in[14];
    const float* t2_Wk = (const float*)d_in[15];
    const float* t2_bk = (const float*)d_in[16];
    const float* t2_Wv = (const float*)d_in[17];
    const float* t2_bv = (const float*)d_in[18];
    const float* t2_We = (const float*)d_in[19];
    const float* t2_Ws = (const float*)d_in[20];
    const float* t2_bs = (const float*)d_in[21];
    const float* fc1_W = (const float*)d_in[22];
    const float* fc1_b = (const float*)d_in[23];
    const float* fc2_W = (const float*)d_in[24];
    const float* fc2_b = (const float*)d_in[25];

    char* ws = (char*)d_ws;
    size_t off = 0;
    auto alloc = [&](size_t bytes) -> void* {
        void* p = ws + off;
        off = (off + bytes + 255) & ~(size_t)255;
        return p;
    };

    ushort_t* qkvs = (ushort_t*)alloc((size_t)N_NODES * NCAT * 2);  // q|k|v|skip bf16
    float* x1   = (float*)alloc((size_t)N_NODES * HC * 4);
    float* macc = (float*)alloc((size_t)N_NODES * HC * 4);
    float* mbuf = (float*)alloc((size_t)N_NODES * NH * 4);
    float* dbuf = (float*)alloc((size_t)N_NODES * NH * 4);
    float* psum = (float*)alloc((size_t)NB * HC * 4);
    float* pmaxb= (float*)alloc((size_t)NB * HC * 4);
    float* hsum = (float*)alloc((size_t)NB * 1024 * 4);
    int*   cnt  = (int*)alloc((size_t)NB * 4);
    // CSR
    int* deg    = (int*)alloc((size_t)N_NODES * 4);
    int* rowptr = (int*)alloc((size_t)(N_NODES + 1) * 4);
    int* cursor = (int*)alloc((size_t)N_NODES * 4);
    int* perm   = (int*)alloc((size_t)N_EDGES * 4);
    int* psrc   = (int*)alloc((size_t)N_EDGES * 4);
    // bf16 activations
    ushort_t* x_b  = (ushort_t*)alloc((size_t)N_NODES * IN_CH * 2);
    ushort_t* x1_b = (ushort_t*)alloc((size_t)N_NODES * HC * 2);
    // pre-padded bf16 edge_attr [E, 96]
    ushort_t* ea_b = (ushort_t*)alloc((size_t)N_EDGES * EDP * 2);
    // weights bf16
    ushort_t* wcat1 = (ushort_t*)alloc((size_t)NCAT * IN_CH * 2);
    ushort_t* wcat2 = (ushort_t*)alloc((size_t)NCAT * HC * 2);
    ushort_t* w1e   = (ushort_t*)alloc((size_t)HC * EDP * 2);
    ushort_t* w2e   = (ushort_t*)alloc((size_t)HC * EDP * 2);
    float* bcat1 = (float*)alloc((size_t)NCAT * 4);
    float* bcat2 = (float*)alloc((size_t)NCAT * 4);

    // remaining -> bf16 edge-feature chunk buffer eb [EC, HC]
    size_t remain = (ws_size > off) ? (ws_size - off) : 0;
    ushort_t* eb = (ushort_t*)(ws + off);
    size_t per_edge = (size_t)HC * 2;  // 1 KiB
    int EC;
    if (remain >= (size_t)N_EDGES * per_edge) {
        EC = N_EDGES;
    } else {
        EC = (int)(remain / per_edge);
        EC &= ~255;
        if (EC <= 0) EC = 256;
        if (EC > N_EDGES) EC = N_EDGES;
    }
    (void)in_sizes; (void)n_in; (void)out_size;

    const int NHC = N_NODES * HC;

    // ---- CSR build
    hipLaunchKernelGGL(k_zero_i, dim3(79), dim3(256), 0, stream, deg, N_NODES);
    hipLaunchKernelGGL(k_hist, dim3((N_EDGES + 255) / 256), dim3(256), 0, stream, dst, deg);
    hipLaunchKernelGGL(k_scan, dim3(1), dim3(1024), 0, stream, deg, rowptr);
    hipLaunchKernelGGL(k_copy_i, dim3(79), dim3(256), 0, stream, rowptr, cursor, N_NODES);
    hipLaunchKernelGGL(k_scatter, dim3((N_EDGES + 255) / 256), dim3(256), 0, stream,
                       src, dst, cursor, perm, psrc);

    // ---- conversions
    hipLaunchKernelGGL(k_cvt_pad, dim3(1024), dim3(256), 0, stream, x, x_b, N_NODES, IN_CH, IN_CH);
    hipLaunchKernelGGL(k_cvt_pad, dim3(4096), dim3(256), 0, stream, ea, ea_b, N_EDGES, ED, EDP);
    hipLaunchKernelGGL(k_cvt_wt, dim3(256), dim3(256), 0, stream, t1_Wq, wcat1 + (size_t)0 * HC * IN_CH, IN_CH, HC, IN_CH);
    hipLaunchKernelGGL(k_cvt_wt, dim3(256), dim3(256), 0, stream, t1_Wk, wcat1 + (size_t)1 * HC * IN_CH, IN_CH, HC, IN_CH);
    hipLaunchKernelGGL(k_cvt_wt, dim3(256), dim3(256), 0, stream, t1_Wv, wcat1 + (size_t)2 * HC * IN_CH, IN_CH, HC, IN_CH);
    hipLaunchKernelGGL(k_cvt_wt, dim3(256), dim3(256), 0, stream, t1_Ws, wcat1 + (size_t)3 * HC * IN_CH, IN_CH, HC, IN_CH);
    hipLaunchKernelGGL(k_cvt_wt, dim3(1024), dim3(256), 0, stream, t2_Wq, wcat2 + (size_t)0 * HC * HC, HC, HC, HC);
    hipLaunchKernelGGL(k_cvt_wt, dim3(1024), dim3(256), 0, stream, t2_Wk, wcat2 + (size_t)1 * HC * HC, HC, HC, HC);
    hipLaunchKernelGGL(k_cvt_wt, dim3(1024), dim3(256), 0, stream, t2_Wv, wcat2 + (size_t)2 * HC * HC, HC, HC, HC);
    hipLaunchKernelGGL(k_cvt_wt, dim3(1024), dim3(256), 0, stream, t2_Ws, wcat2 + (size_t)3 * HC * HC, HC, HC, HC);
    hipLaunchKernelGGL(k_cvt_wt, dim3(192), dim3(256), 0, stream, t1_We, w1e, ED, HC, EDP);
    hipLaunchKernelGGL(k_cvt_wt, dim3(192), dim3(256), 0, stream, t2_We, w2e, ED, HC, EDP);
    hipLaunchKernelGGL(k_bcat, dim3(8), dim3(256), 0, stream, t1_bq, t1_bk, t1_bv, t1_bs, bcat1);
    hipLaunchKernelGGL(k_bcat, dim3(8), dim3(256), 0, stream, t2_bq, t2_bk, t2_bv, t2_bs, bcat2);

    auto run_layer = [&](const ushort_t* xin_b, int Kin, const ushort_t* wcat,
                         const float* bcat, const ushort_t* we,
                         float* xout, ushort_t* xoutb, int poolmode) {
        // fused QKVS GEMM: [N_NODES, Kin] @ [Kin, 2048] -> qkvs bf16
        {
            int mt = (N_NODES + 127) / 128;
            int nt = NCAT / 128;
            hipLaunchKernelGGL(k_mfma_gemm, dim3(mt * nt), dim3(256), 0, stream,
                               xin_b, wcat, bcat, qkvs, N_NODES, Kin, NCAT);
        }
        // edge-phase state init: only dbuf needed (isolated-node guard in epi2);
        // k_edge fresh-inits per-node state on its first chunk.
        hipLaunchKernelGGL(k_fill, dim3(512), dim3(256), 0, stream, dbuf, 0.f, N_NODES * NH);

        // chunked: e-GEMM (gathered, bf16 out) + fused edge pass
        for (int e0 = 0; e0 < N_EDGES; e0 += EC) {
            int ec = (N_EDGES - e0 < EC) ? (N_EDGES - e0) : EC;
            int gm = (ec + 127) / 128;
            hipLaunchKernelGGL(k_egemm, dim3(gm * 4), dim3(256), 0, stream,
                               ea_b, we, eb, perm, e0, ec);
            hipLaunchKernelGGL(k_edge, dim3(N_NODES), dim3(128), 0, stream,
                               qkvs, eb, psrc, rowptr, macc, mbuf, dbuf, e0, e0 + ec);
        }
        hipLaunchKernelGGL(k_epi2, dim3(2048), dim3(256), 0, stream,
                           macc, dbuf, qkvs, xout, xoutb, NHC);

        // pooling
        hipLaunchKernelGGL(k_fill, dim3(128), dim3(256), 0, stream, psum, 0.f, NB * HC);
        hipLaunchKernelGGL(k_fill, dim3(128), dim3(256), 0, stream, pmaxb, -1e30f, NB * HC);
        hipLaunchKernelGGL(k_pool2, dim3(NB, 8), dim3(256), 0, stream, xout, batch, psum, pmaxb, cnt);
        hipLaunchKernelGGL(k_poolfin, dim3((NB * 1024 + 255) / 256), dim3(256), 0, stream,
                           psum, pmaxb, cnt, hsum, poolmode);
    };

    // layer 1: x_b (N,128) -> x1 (+x1_b) ; layer 2: x1_b (N,512) -> x1
    run_layer(x_b, IN_CH, wcat1, bcat1, w1e, x1, x1_b, /*poolmode=*/0);
    run_layer(x1_b, HC, wcat2, bcat2, w2e, x1, (ushort_t*)nullptr, /*poolmode=*/1);

    hipLaunchKernelGGL(k_head, dim3(NB), dim3(256), 0, stream,
                       hsum, fc1_W, fc1_b, fc2_W, fc2_b, (float*)d_out);
}

// Round 13
// 727.908 us; speedup vs baseline: 1.1507x; 1.1507x over previous
//
#include <hip/hip_runtime.h>
#include <cstdint>
#include <cstddef>

#define N_NODES 20000
#define N_EDGES 160000
#define IN_CH   128
#define NH      16
#define CD      32
#define HC      512   // NH*CD
#define ED      93
#define EDP     96    // ED padded to multiple of 32
#define NB      64
#define NCAT    2048  // q|k|v|skip GEMM output cols (all bf16)

typedef __attribute__((ext_vector_type(8))) short short8;
typedef __attribute__((ext_vector_type(4))) float f32x4;
typedef unsigned short ushort_t;

// ---------------------------------------------------------------- utilities

__device__ inline void atomicMaxF(float* addr, float val) {
    unsigned int* ua = (unsigned int*)addr;
    unsigned int old = *ua;
    while (__uint_as_float(old) < val) {
        unsigned int assumed = old;
        old = atomicCAS(ua, assumed, __float_as_uint(val));
        if (old == assumed) break;
    }
}

__device__ inline ushort_t f2bf(float f) {
    unsigned int u = __float_as_uint(f);
    u = (u + 0x7FFF + ((u >> 16) & 1)) >> 16;   // RNE
    return (ushort_t)u;
}
__device__ inline float bf2f(ushort_t u) {
    return __uint_as_float((unsigned)u << 16);
}
__device__ inline void unpack8(uint4 u, float* o) {
    o[0] = bf2f((ushort_t)(u.x & 0xffff)); o[1] = bf2f((ushort_t)(u.x >> 16));
    o[2] = bf2f((ushort_t)(u.y & 0xffff)); o[3] = bf2f((ushort_t)(u.y >> 16));
    o[4] = bf2f((ushort_t)(u.z & 0xffff)); o[5] = bf2f((ushort_t)(u.z >> 16));
    o[6] = bf2f((ushort_t)(u.w & 0xffff)); o[7] = bf2f((ushort_t)(u.w >> 16));
}

// async global->LDS, 16B per lane; lds dest = wave-uniform base + lane*16
__device__ inline void gload_lds16(const void* g, void* l) {
    __builtin_amdgcn_global_load_lds(
        (const __attribute__((address_space(1))) void*)g,
        (__attribute__((address_space(3))) void*)l, 16, 0, 0);
}

__global__ void k_fill(float* __restrict__ p, float v, int n) {
    int i = blockIdx.x * blockDim.x + threadIdx.x;
    int stride = gridDim.x * blockDim.x;
    for (; i < n; i += stride) p[i] = v;
}
__global__ void k_zero_i(int* __restrict__ p, int n) {
    int i = blockIdx.x * blockDim.x + threadIdx.x;
    int stride = gridDim.x * blockDim.x;
    for (; i < n; i += stride) p[i] = 0;
}
__global__ void k_copy_i(const int* __restrict__ a, int* __restrict__ b, int n) {
    int i = blockIdx.x * blockDim.x + threadIdx.x;
    int stride = gridDim.x * blockDim.x;
    for (; i < n; i += stride) b[i] = a[i];
}

// f32 [M,K] -> bf16 [M,Kp] zero-padded rows
__global__ void k_cvt_pad(const float* __restrict__ in, ushort_t* __restrict__ out,
                          int M, int K, int Kp) {
    int i = blockIdx.x * blockDim.x + threadIdx.x;
    int stride = gridDim.x * blockDim.x;
    int total = M * Kp;
    for (; i < total; i += stride) {
        int m = i / Kp, k = i - m * Kp;
        out[i] = (k < K) ? f2bf(in[(size_t)m * K + k]) : (ushort_t)0;
    }
}

// 4x W [K,N] f32 -> Wt[y][N,Kp] bf16 (transpose + pad); source picked by blockIdx.y
__global__ void k_cvt_wt4(const float* __restrict__ W0, const float* __restrict__ W1,
                          const float* __restrict__ W2, const float* __restrict__ W3,
                          ushort_t* __restrict__ Wt, int K, int N, int Kp) {
    int y = blockIdx.y;
    const float* W = (y == 0) ? W0 : (y == 1) ? W1 : (y == 2) ? W2 : W3;
    ushort_t* out = Wt + (size_t)y * N * Kp;
    int i = blockIdx.x * blockDim.x + threadIdx.x;
    int stride = gridDim.x * blockDim.x;
    int total = N * Kp;
    for (; i < total; i += stride) {
        int n = i / Kp, k = i - n * Kp;
        out[i] = (k < K) ? f2bf(W[(size_t)k * N + n]) : (ushort_t)0;
    }
}

// W [K,N] f32 -> Wt [N,Kp] bf16 (transpose + pad)
__global__ void k_cvt_wt(const float* __restrict__ W, ushort_t* __restrict__ Wt,
                         int K, int N, int Kp) {
    int i = blockIdx.x * blockDim.x + threadIdx.x;
    int stride = gridDim.x * blockDim.x;
    int total = N * Kp;
    for (; i < total; i += stride) {
        int n = i / Kp, k = i - n * Kp;
        Wt[i] = (k < K) ? f2bf(W[(size_t)k * N + n]) : (ushort_t)0;
    }
}

// bcat[2048] = bq|bk|bv|bs
__global__ void k_bcat(const float* __restrict__ bq, const float* __restrict__ bk,
                       const float* __restrict__ bv, const float* __restrict__ bs,
                       float* __restrict__ out) {
    int i = blockIdx.x * blockDim.x + threadIdx.x;
    if (i >= NCAT) return;
    int s = i >> 9, j = i & 511;
    float v = (s == 0) ? bq[j] : (s == 1) ? bk[j] : (s == 2) ? bv[j] : bs[j];
    out[i] = v;
}

// psum = 0, pmax = -1e30 in one launch
__global__ void k_poolinit(float* __restrict__ psum, float* __restrict__ pmax) {
    int i = blockIdx.x * blockDim.x + threadIdx.x;
    int stride = gridDim.x * blockDim.x;
    for (; i < NB * HC; i += stride) { psum[i] = 0.f; pmax[i] = -1e30f; }
}

// ---------------------------------------------------------------- CSR build

__global__ void k_hist(const int* __restrict__ dst, int* __restrict__ deg) {
    int i = blockIdx.x * blockDim.x + threadIdx.x;
    if (i < N_EDGES) atomicAdd(&deg[dst[i]], 1);
}

__global__ __launch_bounds__(1024) void k_scan(const int* __restrict__ deg,
                                               int* __restrict__ rowptr) {
    __shared__ int part[1024];
    int t = threadIdx.x;
    int base = t * 20;
    int loc[20];
    int s = 0;
#pragma unroll
    for (int i = 0; i < 20; ++i) {
        int idx = base + i;
        int v = (idx < N_NODES) ? deg[idx] : 0;
        loc[i] = s; s += v;
    }
    part[t] = s;
    __syncthreads();
    for (int off = 1; off < 1024; off <<= 1) {
        int v = (t >= off) ? part[t - off] : 0;
        __syncthreads();
        part[t] += v;
        __syncthreads();
    }
    int pre = (t > 0) ? part[t - 1] : 0;
#pragma unroll
    for (int i = 0; i < 20; ++i) {
        int idx = base + i;
        if (idx < N_NODES) rowptr[idx] = pre + loc[i];
    }
    if (t == 1023) rowptr[N_NODES] = part[1023];
}

__global__ void k_scatter(const int* __restrict__ src, const int* __restrict__ dst,
                          int* __restrict__ cursor, int* __restrict__ perm,
                          int* __restrict__ psrc) {
    int i = blockIdx.x * blockDim.x + threadIdx.x;
    if (i >= N_EDGES) return;
    int d = dst[i];
    int p = atomicAdd(&cursor[d], 1);
    perm[p] = i;
    psrc[p] = src[i];
}

// ---------------------------------------------------------------- MFMA GEMM (QKVS)
// Yb[M,N](bf16) = A[M,K](bf16) @ Bt[N,K]^T + bias. BK=64, 128x128 tile, 4 waves.
// 1-D grid n-fastest + bijective XCD swizzle. LDS rows 128B.
// Staging via global_load_lds with pre-swizzled global source.
// Epilogue: LDS bounce; copy-out is row-contiguous per 16-lane group
// (one wave-instruction = 4 rows x 256B coalesced).

__global__ __launch_bounds__(256) void k_mfma_gemm(
    const ushort_t* __restrict__ A, const ushort_t* __restrict__ Bt,
    const float* __restrict__ bias, ushort_t* __restrict__ Yb,
    int M, int K, int N) {
    __shared__ char smem[32768];
    char* As = smem;
    char* Bs = smem + 16384;

    int tid  = threadIdx.x;
    int lane = tid & 63, wave = tid >> 6;
    int l15 = lane & 15, lg = lane >> 4;
    int nt = N >> 7;
    int nwg = gridDim.x;
    int bid = blockIdx.x;
    int wg;
    if ((nwg & 7) == 0) { int cpx = nwg >> 3; wg = (bid & 7) * cpx + (bid >> 3); }
    else wg = bid;
    int bm = (wg / nt) * 128, bn = (wg % nt) * 128;
    int wm = (wave >> 1) * 64, wn = (wave & 1) * 64;

    f32x4 acc[4][4] = {};

    // staging lane decomposition: sr = sub-row (0..7), su = dest slot, gu = source unit
    int sr = lane >> 3;
    int su = lane & 7;
    int gu = su ^ sr;

    for (int k0 = 0; k0 < K; k0 += 64) {
#pragma unroll
        for (int i = 0; i < 4; ++i) {
            int rloc = wave * 32 + i * 8;          // wave-uniform row base
            int row = rloc + sr;                   // per-lane row
            if (bm + row < M)
                gload_lds16(A + (size_t)(bm + row) * K + k0 + gu * 8, As + rloc * 128);
            gload_lds16(Bt + (size_t)(bn + row) * K + k0 + gu * 8, Bs + rloc * 128);
        }
        __syncthreads();

#pragma unroll
        for (int ks = 0; ks < 2; ++ks) {
            short8 af[4], bfr[4];
#pragma unroll
            for (int mr = 0; mr < 4; ++mr) {
                int r = wm + mr * 16 + l15;
                af[mr] = *(const short8*)(As + r * 128 + (((ks * 4 + lg) ^ (r & 7)) << 4));
            }
#pragma unroll
            for (int nc = 0; nc < 4; ++nc) {
                int r = wn + nc * 16 + l15;
                bfr[nc] = *(const short8*)(Bs + r * 128 + (((ks * 4 + lg) ^ (r & 7)) << 4));
            }
#pragma unroll
            for (int mr = 0; mr < 4; ++mr)
#pragma unroll
                for (int nc = 0; nc < 4; ++nc)
                    acc[mr][nc] = __builtin_amdgcn_mfma_f32_16x16x32_bf16(
                        af[mr], bfr[nc], acc[mr][nc], 0, 0, 0);
        }
        __syncthreads();
    }

    // epilogue: bf16 C tile into LDS (128 rows x 256B, 16B-unit XOR swizzle)
    char* Cs = smem;
#pragma unroll
    for (int mr = 0; mr < 4; ++mr) {
#pragma unroll
        for (int nc = 0; nc < 4; ++nc) {
            int coll = wn + nc * 16 + l15;
            float b = bias ? bias[bn + coll] : 0.f;
            int u0 = coll >> 3;
#pragma unroll
            for (int j = 0; j < 4; ++j) {
                int row = wm + mr * 16 + lg * 4 + j;
                int u = u0 ^ (row & 7);
                *(ushort_t*)(Cs + row * 256 + (u << 4) + ((coll & 7) << 1)) =
                    f2bf(acc[mr][nc][j] + b);
            }
        }
    }
    __syncthreads();
    // copy-out: 16 lanes cover one 256B row; wave-instr = 4 rows coalesced
    {
        int rsub = tid >> 4;      // 0..15
        int un   = tid & 15;      // 16B unit within row
#pragma unroll
        for (int i = 0; i < 8; ++i) {
            int row = i * 16 + rsub;
            int gr = bm + row;
            if (gr < M) {
                int u = un ^ (row & 7);
                *(uint4*)(Yb + (size_t)gr * N + bn + un * 8) =
                    *(const uint4*)(Cs + row * 256 + (u << 4));
            }
        }
    }
}

// ---------------------------------------------------------------- edge GEMM
// eb[r, :512] = ea_b[perm[e0+r], :96] @ We[512,96]^T (bf16). Full-K single-stage.

#define EG_LDSB 49152

__global__ __launch_bounds__(256) void k_egemm(
    const ushort_t* __restrict__ Ab, const ushort_t* __restrict__ Bt,
    ushort_t* __restrict__ Yb, const int* __restrict__ perm,
    int pbase, int ec) {
    __shared__ char smem[EG_LDSB];
    char* As = smem;
    char* Bs = smem + 24576;

    int tid  = threadIdx.x;
    int lane = tid & 63, wave = tid >> 6;
    int l15 = lane & 15, lg = lane >> 4;
    int nwg = gridDim.x;
    int bid = blockIdx.x;
    int wg;
    if ((nwg & 7) == 0) { int cpx = nwg >> 3; wg = (bid & 7) * cpx + (bid >> 3); }
    else wg = bid;
    int bm = (wg >> 2) * 128;
    int n0 = (wg & 3) * 128;
    int wm = (wave >> 1) * 64, wn = (wave & 1) * 64;

    int srow = tid >> 1;
    int h    = tid & 1;
    int ssw  = ((srow >> 1) & 3) << 4;
    {
        int gm = bm + srow;
        uint4 va[6];
#pragma unroll
        for (int i = 0; i < 6; ++i) { va[i].x = va[i].y = va[i].z = va[i].w = 0; }
        if (gm < ec) {
            int ar = perm[pbase + gm];
            const uint4* ga = (const uint4*)(Ab + (size_t)ar * EDP + h * 48);
#pragma unroll
            for (int i = 0; i < 6; ++i) va[i] = ga[i];
        }
        char* dsta = As + srow * 192;
#pragma unroll
        for (int i = 0; i < 6; ++i) {
            int c = h * 96 + i * 16;
            *(uint4*)(dsta + ((c & ~63) | ((c & 63) ^ ssw))) = va[i];
        }
        uint4 vb[6];
        {
            const uint4* gb = (const uint4*)(Bt + (size_t)(n0 + srow) * EDP + h * 48);
#pragma unroll
            for (int i = 0; i < 6; ++i) vb[i] = gb[i];
        }
        char* dstb = Bs + srow * 192;
#pragma unroll
        for (int i = 0; i < 6; ++i) {
            int c = h * 96 + i * 16;
            *(uint4*)(dstb + ((c & ~63) | ((c & 63) ^ ssw))) = vb[i];
        }
    }
    __syncthreads();

    int fsw = ((l15 >> 1) & 3) << 4;

    f32x4 acc[4][4] = {};
#pragma unroll
    for (int ks = 0; ks < 3; ++ks) {
        short8 af[4], bfr[4];
#pragma unroll
        for (int mr = 0; mr < 4; ++mr) {
            int r = wm + mr * 16 + l15;
            int c = ks * 64 + ((lg * 16) ^ fsw);
            af[mr] = *(const short8*)(As + r * 192 + c);
        }
#pragma unroll
        for (int nc = 0; nc < 4; ++nc) {
            int r = wn + nc * 16 + l15;
            int c = ks * 64 + ((lg * 16) ^ fsw);
            bfr[nc] = *(const short8*)(Bs + r * 192 + c);
        }
#pragma unroll
        for (int mr = 0; mr < 4; ++mr)
#pragma unroll
            for (int nc = 0; nc < 4; ++nc)
                acc[mr][nc] = __builtin_amdgcn_mfma_f32_16x16x32_bf16(
                    af[mr], bfr[nc], acc[mr][nc], 0, 0, 0);
    }
    __syncthreads();

    char* Cs = smem;   // 128 rows * 288B stride = 36864
#pragma unroll
    for (int mr = 0; mr < 4; ++mr) {
#pragma unroll
        for (int nc = 0; nc < 4; ++nc) {
            int col = wn + nc * 16 + l15;
#pragma unroll
            for (int j = 0; j < 4; ++j) {
                int row = wm + mr * 16 + lg * 4 + j;
                *(ushort_t*)(Cs + row * 288 + col * 2) = f2bf(acc[mr][nc][j]);
            }
        }
    }
    __syncthreads();

    // copy-out: 16 lanes cover one 256B row segment; coalesced
    {
        int rsub = tid >> 4;
        int un   = tid & 15;
#pragma unroll
        for (int i = 0; i < 8; ++i) {
            int row = i * 16 + rsub;
            if (bm + row < ec) {
                *(uint4*)(Yb + (size_t)(bm + row) * HC + n0 + un * 8) =
                    *(const uint4*)(Cs + row * 288 + un * 16);
            }
        }
    }
}

// ---------------------------------------------------------------- fused edge phase
// One block (128 thr = 2 waves) per dst node. Wave w handles edges lo+w, lo+w+2,...
// Each lane owns 8 channels (16B loads). Online softmax; LDS merge of 2 states.
// fresh = node's first chunk -> init state in-register (no macc/mbuf read).

__global__ __launch_bounds__(128) void k_edge(
    const ushort_t* __restrict__ qkvs, const ushort_t* __restrict__ eb,
    const int* __restrict__ psrc, const int* __restrict__ rowptr,
    float* __restrict__ macc, float* __restrict__ mbuf, float* __restrict__ dbuf,
    int e0, int e1) {
    int n = blockIdx.x;
    int beg = rowptr[n], end = rowptr[n + 1];
    int lo = beg > e0 ? beg : e0;
    int hi = end < e1 ? end : e1;
    if (lo >= hi) return;

    int t = threadIdx.x;
    int w = t >> 6;
    int lane = t & 63;
    int c0 = lane * 8;
    int h = lane >> 2;
    bool fresh = (beg >= e0);

    float q[8];
    unpack8(*(const uint4*)(qkvs + (size_t)n * NCAT + c0), q);

    float mm, dd, a[8];
    if (w == 0 && !fresh) {
        mm = mbuf[n * NH + h];
        dd = dbuf[n * NH + h];
        float4 a0 = *(const float4*)(macc + (size_t)n * HC + c0);
        float4 a1 = *(const float4*)(macc + (size_t)n * HC + c0 + 4);
        a[0] = a0.x; a[1] = a0.y; a[2] = a0.z; a[3] = a0.w;
        a[4] = a1.x; a[5] = a1.y; a[6] = a1.z; a[7] = a1.w;
    } else {
        mm = -1e30f; dd = 0.f;
#pragma unroll
        for (int j = 0; j < 8; ++j) a[j] = 0.f;
    }

    int i = lo + w;
    uint4 ku4, vu4, eu4;
    if (i < hi) {
        int sn = psrc[i];
        ku4 = *(const uint4*)(qkvs + (size_t)sn * NCAT + 512 + c0);
        vu4 = *(const uint4*)(qkvs + (size_t)sn * NCAT + 1024 + c0);
        eu4 = *(const uint4*)(eb + (size_t)(i - e0) * HC + c0);
    }
    while (i < hi) {
        uint4 kc = ku4, vc = vu4, ec = eu4;
        int inext = i + 2;
        if (inext < hi) {
            int sn2 = psrc[inext];
            ku4 = *(const uint4*)(qkvs + (size_t)sn2 * NCAT + 512 + c0);
            vu4 = *(const uint4*)(qkvs + (size_t)sn2 * NCAT + 1024 + c0);
            eu4 = *(const uint4*)(eb + (size_t)(inext - e0) * HC + c0);
        }
        float kk[8], vv[8], ee[8];
        unpack8(kc, kk); unpack8(vc, vv); unpack8(ec, ee);
        float part = 0.f;
#pragma unroll
        for (int j = 0; j < 8; ++j) part += q[j] * (kk[j] + ee[j]);
        part += __shfl_xor(part, 1);
        part += __shfl_xor(part, 2);
        float s = part * 0.17677669529663687f;   // /sqrt(32)
        float mn = fmaxf(mm, s);
        float sc = __expf(mm - mn);
        float p  = __expf(s - mn);
        dd = dd * sc + p;
        mm = mn;
#pragma unroll
        for (int j = 0; j < 8; ++j) a[j] = a[j] * sc + p * (vv[j] + ee[j]);
        i = inext;
    }

    // merge the two wave states
    __shared__ float sm_acc[512];
    __shared__ float sm_m[16];
    __shared__ float sm_d[16];
    if (w == 1) {
#pragma unroll
        for (int j = 0; j < 8; ++j) sm_acc[c0 + j] = a[j];
        if ((lane & 3) == 0) { sm_m[h] = mm; sm_d[h] = dd; }
    }
    __syncthreads();
    if (w == 0) {
        float m1 = sm_m[h], d1 = sm_d[h];
        float M = fmaxf(mm, m1);
        float sc0 = __expf(mm - M);
        float sc1 = __expf(m1 - M);
        dd = dd * sc0 + d1 * sc1;
        float4 o0, o1;
        o0.x = a[0] * sc0 + sm_acc[c0 + 0] * sc1;
        o0.y = a[1] * sc0 + sm_acc[c0 + 1] * sc1;
        o0.z = a[2] * sc0 + sm_acc[c0 + 2] * sc1;
        o0.w = a[3] * sc0 + sm_acc[c0 + 3] * sc1;
        o1.x = a[4] * sc0 + sm_acc[c0 + 4] * sc1;
        o1.y = a[5] * sc0 + sm_acc[c0 + 5] * sc1;
        o1.z = a[6] * sc0 + sm_acc[c0 + 6] * sc1;
        o1.w = a[7] * sc0 + sm_acc[c0 + 7] * sc1;
        *(float4*)(macc + (size_t)n * HC + c0) = o0;
        *(float4*)(macc + (size_t)n * HC + c0 + 4) = o1;
        if ((lane & 3) == 0) { mbuf[n * NH + h] = M; dbuf[n * NH + h] = dd; }
    }
}

// x_out = leaky_relu(macc/d + skip, 0.2); skip read bf16 from qkvs[:,1536:2048]
__global__ void k_epi2(const float* __restrict__ macc, const float* __restrict__ dbuf,
                       const ushort_t* __restrict__ qkvs, float* __restrict__ xout,
                       ushort_t* __restrict__ xoutb, int n) {
    int i = blockIdx.x * blockDim.x + threadIdx.x;
    int stride = gridDim.x * blockDim.x;
    for (; i < n; i += stride) {
        int node = i >> 9, c = i & (HC - 1);
        int h = c >> 5;
        float dd = dbuf[node * NH + h];
        float msg = (dd > 0.f) ? macc[i] / dd : 0.f;
        float sk = bf2f(qkvs[(size_t)node * NCAT + 1536 + c]);
        float v = msg + sk;
        v = v >= 0.f ? v : 0.2f * v;
        xout[i] = v;
        if (xoutb) xoutb[i] = f2bf(v);
    }
}

// ---------------------------------------------------------------- pooling

__global__ __launch_bounds__(256) void k_pool2(
    const float* __restrict__ x, const int* __restrict__ batch,
    float* __restrict__ psum, float* __restrict__ pmax, int* __restrict__ cnt) {
    int b = blockIdx.x;
    int s = blockIdx.y;
    int lo = 0, hi = N_NODES;
    while (lo < hi) { int mid = (lo + hi) >> 1; if (batch[mid] < b) lo = mid + 1; else hi = mid; }
    int beg = lo;
    hi = N_NODES;
    while (lo < hi) { int mid = (lo + hi) >> 1; if (batch[mid] < b + 1) lo = mid + 1; else hi = mid; }
    int end = lo;
    if (s == 0 && threadIdx.x == 0) cnt[b] = end - beg;
    int cn = end - beg;
    int per = (cn + 7) >> 3;
    int nb = beg + s * per;
    int ne = nb + per; if (ne > end) ne = end;
    if (nb >= ne) return;
    int c0 = threadIdx.x * 2;
    float s0 = 0.f, s1 = 0.f, m0 = -1e30f, m1 = -1e30f;
    for (int n = nb; n < ne; ++n) {
        float2 v = *(const float2*)(x + (size_t)n * HC + c0);
        s0 += v.x; s1 += v.y;
        m0 = fmaxf(m0, v.x); m1 = fmaxf(m1, v.y);
    }
    atomicAdd(&psum[b * HC + c0], s0);
    atomicAdd(&psum[b * HC + c0 + 1], s1);
    atomicMaxF(&pmax[b * HC + c0], m0);
    atomicMaxF(&pmax[b * HC + c0 + 1], m1);
}

__global__ void k_poolfin(const float* __restrict__ psum, const float* __restrict__ pmax,
                          const int* __restrict__ cnt, float* __restrict__ hsum, int mode) {
    int i = blockIdx.x * blockDim.x + threadIdx.x;
    if (i >= NB * 1024) return;
    int b = i >> 10, c = i & 1023;
    float val;
    if (c < HC) {
        int ct = cnt[b];
        val = psum[b * HC + c] / (float)(ct > 0 ? ct : 1);
    } else {
        val = pmax[b * HC + (c - HC)];
    }
    if (mode == 0) hsum[i] = val;
    else hsum[i] += val;
}

// ---------------------------------------------------------------- MLP head

__global__ __launch_bounds__(256) void k_head(
    const float* __restrict__ hsum, const float* __restrict__ fc1W,
    const float* __restrict__ fc1b, const float* __restrict__ fc2W,
    const float* __restrict__ fc2b, float* __restrict__ out) {
    int b = blockIdx.x;
    int j = threadIdx.x;
    __shared__ float hs[256];
    float acc = fc1b[j];
    const float* hin = hsum + (size_t)b * 1024;
    for (int k = 0; k < 1024; ++k) {
        acc += hin[k] * fc1W[(size_t)k * 256 + j];
    }
    hs[j] = fmaxf(acc, 0.f);
    __syncthreads();
    if (j < 32) {
        float o = fc2b[j];
        for (int k = 0; k < 256; ++k) o += hs[k] * fc2W[(size_t)k * 32 + j];
        out[b * 32 + j] = o;
    }
}

// ---------------------------------------------------------------- driver

extern "C" void kernel_launch(void* const* d_in, const int* in_sizes, int n_in,
                              void* d_out, int out_size, void* d_ws, size_t ws_size,
                              hipStream_t stream) {
    const float* x      = (const float*)d_in[0];
    const float* ea     = (const float*)d_in[1];
    const int*   ei     = (const int*)d_in[2];
    const int*   batch  = (const int*)d_in[3];
    const int* src = ei;
    const int* dst = ei + N_EDGES;

    const float* t1_Wq = (const float*)d_in[4];
    const float* t1_bq = (const float*)d_in[5];
    const float* t1_Wk = (const float*)d_in[6];
    const float* t1_bk = (const float*)d_in[7];
    const float* t1_Wv = (const float*)d_in[8];
    const float* t1_bv = (const float*)d_in[9];
    const float* t1_We = (const float*)d_in[10];
    const float* t1_Ws = (const float*)d_in[11];
    const float* t1_bs = (const float*)d_in[12];
    const float* t2_Wq = (const float*)d_in[13];
    const float* t2_bq = (const float*)d_in[14];
    const float* t2_Wk = (const float*)d_in[15];
    const float* t2_bk = (const float*)d_in[16];
    const float* t2_Wv = (const float*)d_in[17];
    const float* t2_bv = (const float*)d_in[18];
    const float* t2_We = (const float*)d_in[19];
    const float* t2_Ws = (const float*)d_in[20];
    const float* t2_bs = (const float*)d_in[21];
    const float* fc1_W = (const float*)d_in[22];
    const float* fc1_b = (const float*)d_in[23];
    const float* fc2_W = (const float*)d_in[24];
    const float* fc2_b = (const float*)d_in[25];

    char* ws = (char*)d_ws;
    size_t off = 0;
    auto alloc = [&](size_t bytes) -> void* {
        void* p = ws + off;
        off = (off + bytes + 255) & ~(size_t)255;
        return p;
    };

    ushort_t* qkvs = (ushort_t*)alloc((size_t)N_NODES * NCAT * 2);  // q|k|v|skip bf16
    float* x1   = (float*)alloc((size_t)N_NODES * HC * 4);
    float* macc = (float*)alloc((size_t)N_NODES * HC * 4);
    float* mbuf = (float*)alloc((size_t)N_NODES * NH * 4);
    float* dbuf = (float*)alloc((size_t)N_NODES * NH * 4);
    float* psum = (float*)alloc((size_t)NB * HC * 4);
    float* pmaxb= (float*)alloc((size_t)NB * HC * 4);
    float* hsum = (float*)alloc((size_t)NB * 1024 * 4);
    int*   cnt  = (int*)alloc((size_t)NB * 4);
    // CSR
    int* deg    = (int*)alloc((size_t)N_NODES * 4);
    int* rowptr = (int*)alloc((size_t)(N_NODES + 1) * 4);
    int* cursor = (int*)alloc((size_t)N_NODES * 4);
    int* perm   = (int*)alloc((size_t)N_EDGES * 4);
    int* psrc   = (int*)alloc((size_t)N_EDGES * 4);
    // bf16 activations
    ushort_t* x_b  = (ushort_t*)alloc((size_t)N_NODES * IN_CH * 2);
    ushort_t* x1_b = (ushort_t*)alloc((size_t)N_NODES * HC * 2);
    // pre-padded bf16 edge_attr [E, 96]
    ushort_t* ea_b = (ushort_t*)alloc((size_t)N_EDGES * EDP * 2);
    // weights bf16
    ushort_t* wcat1 = (ushort_t*)alloc((size_t)NCAT * IN_CH * 2);
    ushort_t* wcat2 = (ushort_t*)alloc((size_t)NCAT * HC * 2);
    ushort_t* w1e   = (ushort_t*)alloc((size_t)HC * EDP * 2);
    ushort_t* w2e   = (ushort_t*)alloc((size_t)HC * EDP * 2);
    float* bcat1 = (float*)alloc((size_t)NCAT * 4);
    float* bcat2 = (float*)alloc((size_t)NCAT * 4);

    // remaining -> bf16 edge-feature chunk buffer eb [EC, HC]
    size_t remain = (ws_size > off) ? (ws_size - off) : 0;
    ushort_t* eb = (ushort_t*)(ws + off);
    size_t per_edge = (size_t)HC * 2;  // 1 KiB
    int EC;
    if (remain >= (size_t)N_EDGES * per_edge) {
        EC = N_EDGES;
    } else {
        EC = (int)(remain / per_edge);
        EC &= ~255;
        if (EC <= 0) EC = 256;
        if (EC > N_EDGES) EC = N_EDGES;
    }
    (void)in_sizes; (void)n_in; (void)out_size;

    const int NHC = N_NODES * HC;

    // ---- CSR build
    hipLaunchKernelGGL(k_zero_i, dim3(79), dim3(256), 0, stream, deg, N_NODES);
    hipLaunchKernelGGL(k_hist, dim3((N_EDGES + 255) / 256), dim3(256), 0, stream, dst, deg);
    hipLaunchKernelGGL(k_scan, dim3(1), dim3(1024), 0, stream, deg, rowptr);
    hipLaunchKernelGGL(k_copy_i, dim3(79), dim3(256), 0, stream, rowptr, cursor, N_NODES);
    hipLaunchKernelGGL(k_scatter, dim3((N_EDGES + 255) / 256), dim3(256), 0, stream,
                       src, dst, cursor, perm, psrc);

    // ---- conversions (merged launches)
    hipLaunchKernelGGL(k_cvt_pad, dim3(1024), dim3(256), 0, stream, x, x_b, N_NODES, IN_CH, IN_CH);
    hipLaunchKernelGGL(k_cvt_pad, dim3(4096), dim3(256), 0, stream, ea, ea_b, N_EDGES, ED, EDP);
    hipLaunchKernelGGL(k_cvt_wt4, dim3(256, 4), dim3(256), 0, stream,
                       t1_Wq, t1_Wk, t1_Wv, t1_Ws, wcat1, IN_CH, HC, IN_CH);
    hipLaunchKernelGGL(k_cvt_wt4, dim3(1024, 4), dim3(256), 0, stream,
                       t2_Wq, t2_Wk, t2_Wv, t2_Ws, wcat2, HC, HC, HC);
    hipLaunchKernelGGL(k_cvt_wt, dim3(192), dim3(256), 0, stream, t1_We, w1e, ED, HC, EDP);
    hipLaunchKernelGGL(k_cvt_wt, dim3(192), dim3(256), 0, stream, t2_We, w2e, ED, HC, EDP);
    hipLaunchKernelGGL(k_bcat, dim3(8), dim3(256), 0, stream, t1_bq, t1_bk, t1_bv, t1_bs, bcat1);
    hipLaunchKernelGGL(k_bcat, dim3(8), dim3(256), 0, stream, t2_bq, t2_bk, t2_bv, t2_bs, bcat2);

    auto run_layer = [&](const ushort_t* xin_b, int Kin, const ushort_t* wcat,
                         const float* bcat, const ushort_t* we,
                         float* xout, ushort_t* xoutb, int poolmode) {
        // fused QKVS GEMM: [N_NODES, Kin] @ [Kin, 2048] -> qkvs bf16
        {
            int mt = (N_NODES + 127) / 128;
            int nt = NCAT / 128;
            hipLaunchKernelGGL(k_mfma_gemm, dim3(mt * nt), dim3(256), 0, stream,
                               xin_b, wcat, bcat, qkvs, N_NODES, Kin, NCAT);
        }
        // edge-phase state init: only dbuf needed (isolated-node guard in epi2)
        hipLaunchKernelGGL(k_fill, dim3(512), dim3(256), 0, stream, dbuf, 0.f, N_NODES * NH);

        // chunked: e-GEMM (gathered, bf16 out) + fused edge pass
        for (int e0 = 0; e0 < N_EDGES; e0 += EC) {
            int ec = (N_EDGES - e0 < EC) ? (N_EDGES - e0) : EC;
            int gm = (ec + 127) / 128;
            hipLaunchKernelGGL(k_egemm, dim3(gm * 4), dim3(256), 0, stream,
                               ea_b, we, eb, perm, e0, ec);
            hipLaunchKernelGGL(k_edge, dim3(N_NODES), dim3(128), 0, stream,
                               qkvs, eb, psrc, rowptr, macc, mbuf, dbuf, e0, e0 + ec);
        }
        hipLaunchKernelGGL(k_epi2, dim3(2048), dim3(256), 0, stream,
                           macc, dbuf, qkvs, xout, xoutb, NHC);

        // pooling
        hipLaunchKernelGGL(k_poolinit, dim3(128), dim3(256), 0, stream, psum, pmaxb);
        hipLaunchKernelGGL(k_pool2, dim3(NB, 8), dim3(256), 0, stream, xout, batch, psum, pmaxb, cnt);
        hipLaunchKernelGGL(k_poolfin, dim3((NB * 1024 + 255) / 256), dim3(256), 0, stream,
                           psum, pmaxb, cnt, hsum, poolmode);
    };

    // layer 1: x_b (N,128) -> x1 (+x1_b) ; layer 2: x1_b (N,512) -> x1
    run_layer(x_b, IN_CH, wcat1, bcat1, w1e, x1, x1_b, /*poolmode=*/0);
    run_layer(x1_b, HC, wcat2, bcat2, w2e, x1, (ushort_t*)nullptr, /*poolmode=*/1);

    hipLaunchKernelGGL(k_head, dim3(NB), dim3(256), 0, stream,
                       hsum, fc1_W, fc1_b, fc2_W, fc2_b, (float*)d_out);
}